// Round 1
// baseline (885.059 us; speedup 1.0000x reference)
//
#include <hip/hip_runtime.h>

#define N_ATOMS 65536
#define N_BONDS 131072
#define AF      133     // atom feature dim
#define BT      147     // bond feature total dim
#define BF      14      // bond fdim used (last 14 cols)
#define HID     256
#define NNB     6       // neighbors per atom
#define NM      2048    // molecules

#define ROWS     16     // atom rows per block
#define S_STRIDE 260    // LDS stride for 256-wide tiles (pad past 256)
#define A_STRIDE 136    // LDS stride for 133-wide tiles

// ---------------------------------------------------------------------------
// Kernel 1: inp = atom_features @ Wi + bi ; msg = relu(inp)
// Block: 256 threads, 16 rows x 256 cols output tile; thread = 4x4 micro-tile.
// ---------------------------------------------------------------------------
__global__ __launch_bounds__(256) void k_inp(const float* __restrict__ atom,
                                             const float* __restrict__ Wi,
                                             const float* __restrict__ bi,
                                             float* __restrict__ inp,
                                             float* __restrict__ msg) {
    __shared__ float As[ROWS][A_STRIDE];
    const int base = blockIdx.x * ROWS;
    const int tid  = threadIdx.x;

    for (int idx = tid; idx < ROWS * AF; idx += 256) {
        int r = idx / AF;
        int k = idx - r * AF;
        As[r][k] = atom[(base + r) * AF + k];
    }
    __syncthreads();

    const int tr = tid >> 6;   // 0..3 (row group)
    const int tc = tid & 63;   // 0..63 (col group of 4)
    float acc[4][4] = {};

#pragma unroll 4
    for (int k = 0; k < AF; ++k) {
        float4 w = *(const float4*)&Wi[k * HID + (tc << 2)];
#pragma unroll
        for (int r4 = 0; r4 < 4; ++r4) {
            float s = As[(tr << 2) + r4][k];
            acc[r4][0] = fmaf(s, w.x, acc[r4][0]);
            acc[r4][1] = fmaf(s, w.y, acc[r4][1]);
            acc[r4][2] = fmaf(s, w.z, acc[r4][2]);
            acc[r4][3] = fmaf(s, w.w, acc[r4][3]);
        }
    }

    float4 bv = *(const float4*)&bi[tc << 2];
#pragma unroll
    for (int r4 = 0; r4 < 4; ++r4) {
        int row = base + (tr << 2) + r4;
        float4 o;
        o.x = acc[r4][0] + bv.x;
        o.y = acc[r4][1] + bv.y;
        o.z = acc[r4][2] + bv.z;
        o.w = acc[r4][3] + bv.w;
        *(float4*)&inp[row * HID + (tc << 2)] = o;
        float4 m;
        m.x = fmaxf(o.x, 0.0f);
        m.y = fmaxf(o.y, 0.0f);
        m.z = fmaxf(o.z, 0.0f);
        m.w = fmaxf(o.w, 0.0f);
        *(float4*)&msg[row * HID + (tc << 2)] = m;
    }
}

// ---------------------------------------------------------------------------
// Kernel 2: one message-passing iteration.
//   nei_a = sum_t msg_in[a2a[i,t]]      (256-wide, gathered into LDS)
//   nei_b = sum_t fb[a2b[i,t]]          (14-wide,  gathered into LDS)
//   msg_out = relu(inp + [nei_a|nei_b] @ Wh + bh)
// ---------------------------------------------------------------------------
__global__ __launch_bounds__(256) void k_iter(const float* __restrict__ msg_in,
                                              const float* __restrict__ inp,
                                              const float* __restrict__ f_bonds,
                                              const int*  __restrict__ a2a,
                                              const int*  __restrict__ a2b,
                                              const float* __restrict__ Wh,
                                              const float* __restrict__ bh,
                                              float* __restrict__ msg_out) {
    __shared__ float S[ROWS][S_STRIDE];
    __shared__ float NBs[ROWS][BF];
    __shared__ int   a2a_l[ROWS * NNB];
    __shared__ int   a2b_l[ROWS * NNB];

    const int base = blockIdx.x * ROWS;
    const int tid  = threadIdx.x;

    if (tid < ROWS * NNB) {
        a2a_l[tid] = a2a[base * NNB + tid];
        a2b_l[tid] = a2b[base * NNB + tid];
    }
    __syncthreads();

    // gather nei_a sums: thread = column j
    {
        const int j = tid;
        for (int r = 0; r < ROWS; ++r) {
            float s = 0.0f;
#pragma unroll
            for (int t = 0; t < NNB; ++t)
                s += msg_in[a2a_l[r * NNB + t] * HID + j];
            S[r][j] = s;
        }
    }
    // gather nei_b sums (14 cols x 16 rows = 224 threads)
    if (tid < ROWS * BF) {
        int r = tid / BF;
        int c = tid - r * BF;
        float s = 0.0f;
#pragma unroll
        for (int t = 0; t < NNB; ++t)
            s += f_bonds[a2b_l[r * NNB + t] * BT + (BT - BF) + c];
        NBs[r][c] = s;
    }
    __syncthreads();

    const int tr = tid >> 6;
    const int tc = tid & 63;
    float acc[4][4] = {};

#pragma unroll 4
    for (int k = 0; k < HID; ++k) {
        float4 w = *(const float4*)&Wh[k * HID + (tc << 2)];
#pragma unroll
        for (int r4 = 0; r4 < 4; ++r4) {
            float s = S[(tr << 2) + r4][k];
            acc[r4][0] = fmaf(s, w.x, acc[r4][0]);
            acc[r4][1] = fmaf(s, w.y, acc[r4][1]);
            acc[r4][2] = fmaf(s, w.z, acc[r4][2]);
            acc[r4][3] = fmaf(s, w.w, acc[r4][3]);
        }
    }
#pragma unroll
    for (int kb = 0; kb < BF; ++kb) {
        float4 w = *(const float4*)&Wh[(HID + kb) * HID + (tc << 2)];
#pragma unroll
        for (int r4 = 0; r4 < 4; ++r4) {
            float s = NBs[(tr << 2) + r4][kb];
            acc[r4][0] = fmaf(s, w.x, acc[r4][0]);
            acc[r4][1] = fmaf(s, w.y, acc[r4][1]);
            acc[r4][2] = fmaf(s, w.z, acc[r4][2]);
            acc[r4][3] = fmaf(s, w.w, acc[r4][3]);
        }
    }

    float4 bv = *(const float4*)&bh[tc << 2];
#pragma unroll
    for (int r4 = 0; r4 < 4; ++r4) {
        int row = base + (tr << 2) + r4;
        float4 iv = *(const float4*)&inp[row * HID + (tc << 2)];
        float4 o;
        o.x = fmaxf(iv.x + bv.x + acc[r4][0], 0.0f);
        o.y = fmaxf(iv.y + bv.y + acc[r4][1], 0.0f);
        o.z = fmaxf(iv.z + bv.z + acc[r4][2], 0.0f);
        o.w = fmaxf(iv.w + bv.w + acc[r4][3], 0.0f);
        *(float4*)&msg_out[row * HID + (tc << 2)] = o;
    }
}

// ---------------------------------------------------------------------------
// Kernel 3: a_message = sum_t msg[a2a[i,t]] ;
//           hid = relu([atom_features | a_message] @ Wo + bo)
// ---------------------------------------------------------------------------
__global__ __launch_bounds__(256) void k_final(const float* __restrict__ msg_in,
                                               const float* __restrict__ atom,
                                               const int*  __restrict__ a2a,
                                               const float* __restrict__ Wo,
                                               const float* __restrict__ bo,
                                               float* __restrict__ hid) {
    __shared__ float S[ROWS][S_STRIDE];
    __shared__ float As[ROWS][A_STRIDE];
    __shared__ int   a2a_l[ROWS * NNB];

    const int base = blockIdx.x * ROWS;
    const int tid  = threadIdx.x;

    if (tid < ROWS * NNB) a2a_l[tid] = a2a[base * NNB + tid];
    for (int idx = tid; idx < ROWS * AF; idx += 256) {
        int r = idx / AF;
        int k = idx - r * AF;
        As[r][k] = atom[(base + r) * AF + k];
    }
    __syncthreads();

    {
        const int j = tid;
        for (int r = 0; r < ROWS; ++r) {
            float s = 0.0f;
#pragma unroll
            for (int t = 0; t < NNB; ++t)
                s += msg_in[a2a_l[r * NNB + t] * HID + j];
            S[r][j] = s;
        }
    }
    __syncthreads();

    const int tr = tid >> 6;
    const int tc = tid & 63;
    float acc[4][4] = {};

    // atom-feature part: Wo rows 0..132
#pragma unroll 4
    for (int k = 0; k < AF; ++k) {
        float4 w = *(const float4*)&Wo[k * HID + (tc << 2)];
#pragma unroll
        for (int r4 = 0; r4 < 4; ++r4) {
            float s = As[(tr << 2) + r4][k];
            acc[r4][0] = fmaf(s, w.x, acc[r4][0]);
            acc[r4][1] = fmaf(s, w.y, acc[r4][1]);
            acc[r4][2] = fmaf(s, w.z, acc[r4][2]);
            acc[r4][3] = fmaf(s, w.w, acc[r4][3]);
        }
    }
    // a_message part: Wo rows 133..388
#pragma unroll 4
    for (int k = 0; k < HID; ++k) {
        float4 w = *(const float4*)&Wo[(AF + k) * HID + (tc << 2)];
#pragma unroll
        for (int r4 = 0; r4 < 4; ++r4) {
            float s = S[(tr << 2) + r4][k];
            acc[r4][0] = fmaf(s, w.x, acc[r4][0]);
            acc[r4][1] = fmaf(s, w.y, acc[r4][1]);
            acc[r4][2] = fmaf(s, w.z, acc[r4][2]);
            acc[r4][3] = fmaf(s, w.w, acc[r4][3]);
        }
    }

    float4 bv = *(const float4*)&bo[tc << 2];
#pragma unroll
    for (int r4 = 0; r4 < 4; ++r4) {
        int row = base + (tr << 2) + r4;
        float4 o;
        o.x = fmaxf(acc[r4][0] + bv.x, 0.0f);
        o.y = fmaxf(acc[r4][1] + bv.y, 0.0f);
        o.z = fmaxf(acc[r4][2] + bv.z, 0.0f);
        o.w = fmaxf(acc[r4][3] + bv.w, 0.0f);
        *(float4*)&hid[row * HID + (tc << 2)] = o;
    }
}

// ---------------------------------------------------------------------------
// Kernel 4: segment mean over sorted segment_ids. One block per molecule.
// ---------------------------------------------------------------------------
__global__ __launch_bounds__(256) void k_segmean(const float* __restrict__ hid,
                                                 const int*  __restrict__ seg,
                                                 float* __restrict__ out) {
    const int m = blockIdx.x;
    __shared__ int lohi[2];
    if (threadIdx.x == 0) {
        int lo = 0, hi = N_ATOMS;
        while (lo < hi) { int mid = (lo + hi) >> 1; if (seg[mid] < m) lo = mid + 1; else hi = mid; }
        lohi[0] = lo;
        int lo2 = lo, hi2 = N_ATOMS;
        while (lo2 < hi2) { int mid = (lo2 + hi2) >> 1; if (seg[mid] < m + 1) lo2 = mid + 1; else hi2 = mid; }
        lohi[1] = lo2;
    }
    __syncthreads();
    const int lo = lohi[0], hi = lohi[1];
    const int j = threadIdx.x;
    float s = 0.0f;
    for (int i = lo; i < hi; ++i) s += hid[i * HID + j];
    const int cnt = hi - lo;
    out[m * HID + j] = (cnt > 0) ? (s / (float)cnt) : 0.0f;
}

// ---------------------------------------------------------------------------
extern "C" void kernel_launch(void* const* d_in, const int* in_sizes, int n_in,
                              void* d_out, int out_size, void* d_ws, size_t ws_size,
                              hipStream_t stream) {
    const float* atom    = (const float*)d_in[0];
    const float* f_bonds = (const float*)d_in[1];
    const int*   a2a     = (const int*)d_in[2];
    const int*   a2b     = (const int*)d_in[3];
    const int*   seg     = (const int*)d_in[4];
    const float* Wi      = (const float*)d_in[5];
    const float* bi      = (const float*)d_in[6];
    const float* Wh      = (const float*)d_in[7];
    const float* bh      = (const float*)d_in[8];
    const float* Wo      = (const float*)d_in[9];
    const float* bo      = (const float*)d_in[10];
    float* out = (float*)d_out;

    float* ws   = (float*)d_ws;
    const size_t buf = (size_t)N_ATOMS * HID;   // 16.78M floats = 67MB
    float* inp  = ws;
    float* msg0 = ws + buf;
    float* msg1 = ws + 2 * buf;

    const int nblk = N_ATOMS / ROWS;   // 4096
    dim3 blk(256);

    k_inp<<<nblk, blk, 0, stream>>>(atom, Wi, bi, inp, msg0);
    k_iter<<<nblk, blk, 0, stream>>>(msg0, inp, f_bonds, a2a, a2b, Wh, bh, msg1);
    k_iter<<<nblk, blk, 0, stream>>>(msg1, inp, f_bonds, a2a, a2b, Wh, bh, msg0);
    k_final<<<nblk, blk, 0, stream>>>(msg0, atom, a2a, Wo, bo, msg1);
    k_segmean<<<NM, blk, 0, stream>>>(msg1, seg, out);
}

// Round 2
// 471.748 us; speedup vs baseline: 1.8761x; 1.8761x over previous
//
#include <hip/hip_runtime.h>

#define N_ATOMS 65536
#define AF      133     // atom feature dim
#define BT      147     // bond feature total dim
#define HID     256
#define NNB     6
#define NM      2048

// padded K per GEMM (multiples of 32; zero-padded in both A and W -> exact)
#define KI   160        // k_inp:   atom(133) + pad
#define KH   288        // k_iter:  msg(256) + bond(14) + pad
#define KO   416        // k_final: msg(256) + atom(133) + pad
// LDS strides (elements): K+8 -> row start rotates 20 banks (free 2-way only)
#define LSI  168
#define LSH  296
#define LSO  424

typedef __attribute__((ext_vector_type(8))) short short8;
typedef __attribute__((ext_vector_type(4))) float f32x4;

__device__ __forceinline__ unsigned short f2bf(float f) {
    unsigned u = __builtin_bit_cast(unsigned, f);
    u += 0x7fffu + ((u >> 16) & 1u);     // round-to-nearest-even
    return (unsigned short)(u >> 16);
}
__device__ __forceinline__ float bf2f(unsigned short s) {
    unsigned u = ((unsigned)s) << 16;
    return __builtin_bit_cast(float, u);
}

// ---------------------------------------------------------------------------
// Weight prep: bf16, transposed to [N=256][K], K zero-padded.
// Wi_t[n][k] = Wi[k][n] (k<133)
// Wh_t[n][k] = Wh[k][n] (k<270)   rows: 0..255 msg part, 256..269 bond part
// Wo_t[n][k] = k<256 ? Wo[133+k][n] : (k<389 ? Wo[k-256][n] : 0)
//   (A layout for k_final: cols 0..255 = a_message, 256..388 = atom features)
// ---------------------------------------------------------------------------
__global__ __launch_bounds__(256) void k_prep(const float* __restrict__ Wi,
                                              const float* __restrict__ Wh,
                                              const float* __restrict__ Wo,
                                              unsigned short* __restrict__ Wi_t,
                                              unsigned short* __restrict__ Wh_t,
                                              unsigned short* __restrict__ Wo_t) {
    const int n = blockIdx.x;
    for (int k = threadIdx.x; k < KI; k += 256)
        Wi_t[n * KI + k] = f2bf(k < AF ? Wi[k * HID + n] : 0.f);
    for (int k = threadIdx.x; k < KH; k += 256)
        Wh_t[n * KH + k] = f2bf(k < (HID + 14) ? Wh[k * HID + n] : 0.f);
    for (int k = threadIdx.x; k < KO; k += 256) {
        float v = 0.f;
        if (k < HID)            v = Wo[(AF + k) * HID + n];
        else if (k < HID + AF)  v = Wo[(k - HID) * HID + n];
        Wo_t[n * KO + k] = f2bf(v);
    }
}

// ---------------------------------------------------------------------------
// MFMA core: C[64 x 256] += A_lds[64 x K](bf16) @ W_t[256 x K]^T (bf16)
// wave w owns cols w*64..w*64+63; 4 row-tiles x 4 col-tiles of 16x16x32.
// A-frag:  lane-> A[m=lane&15][k = quad*8 + j]
// B-frag:  lane-> B[k = quad*8 + j][n=lane&15] = W_t[n][k]  (contiguous 16B)
// C/D:     col = lane&15, row = quad*4 + reg
// ---------------------------------------------------------------------------
template<int K, int LS>
__device__ __forceinline__ void mfma_core(const unsigned short* __restrict__ As,
                                          const unsigned short* __restrict__ Wt,
                                          f32x4 (&acc)[4][4], int wave, int lane) {
    const int lm = lane & 15, quad = lane >> 4;
    for (int ks = 0; ks < K; ks += 32) {
        short8 af[4], bf[4];
#pragma unroll
        for (int rt = 0; rt < 4; ++rt)
            af[rt] = *(const short8*)&As[(rt * 16 + lm) * LS + ks + quad * 8];
#pragma unroll
        for (int ct = 0; ct < 4; ++ct)
            bf[ct] = *(const short8*)&Wt[(size_t)(wave * 64 + ct * 16 + lm) * K + ks + quad * 8];
#pragma unroll
        for (int rt = 0; rt < 4; ++rt)
#pragma unroll
            for (int ct = 0; ct < 4; ++ct)
                acc[rt][ct] = __builtin_amdgcn_mfma_f32_16x16x32_bf16(af[rt], bf[ct], acc[rt][ct], 0, 0, 0);
    }
}

// ---------------------------------------------------------------------------
// Kernel 1: inp = atom @ Wi + bi (fp32) ; msg = relu(inp) (bf16)
// ---------------------------------------------------------------------------
__global__ __launch_bounds__(256) void k_inp(const float* __restrict__ atom,
                                             const unsigned short* __restrict__ Wi_t,
                                             const float* __restrict__ bi,
                                             float* __restrict__ inp,
                                             unsigned short* __restrict__ msg) {
    __shared__ unsigned short As[64 * LSI];
    const int tid  = threadIdx.x;
    const int base = blockIdx.x * 64;

    for (int it = tid; it < 64 * KI; it += 256) {
        int r = it / KI, c = it - r * KI;
        float v = (c < AF) ? atom[(size_t)(base + r) * AF + c] : 0.f;
        As[r * LSI + c] = f2bf(v);
    }
    __syncthreads();

    const int lane = tid & 63, wave = tid >> 6;
    f32x4 acc[4][4] = {};
    mfma_core<KI, LSI>(As, Wi_t, acc, wave, lane);

    const int lm = lane & 15, quad = lane >> 4;
#pragma unroll
    for (int ct = 0; ct < 4; ++ct) {
        int col = wave * 64 + ct * 16 + lm;
        float bv = bi[col];
#pragma unroll
        for (int rt = 0; rt < 4; ++rt)
#pragma unroll
            for (int i = 0; i < 4; ++i) {
                int row = base + rt * 16 + quad * 4 + i;
                float v = acc[rt][ct][i] + bv;
                inp[(size_t)row * HID + col] = v;
                msg[(size_t)row * HID + col] = f2bf(fmaxf(v, 0.f));
            }
    }
}

// ---------------------------------------------------------------------------
// Kernel 2: msg_out = relu(inp + [gather_a(msg)|gather_b(fb)] @ Wh + bh)
// ---------------------------------------------------------------------------
__global__ __launch_bounds__(256) void k_iter(const unsigned short* __restrict__ msg_in,
                                              const float* __restrict__ inp,
                                              const float* __restrict__ f_bonds,
                                              const int* __restrict__ a2a,
                                              const int* __restrict__ a2b,
                                              const unsigned short* __restrict__ Wh_t,
                                              const float* __restrict__ bh,
                                              unsigned short* __restrict__ msg_out) {
    __shared__ unsigned short As[64 * LSH];
    __shared__ int a2a_l[64 * NNB];
    __shared__ int a2b_l[64 * NNB];
    const int tid  = threadIdx.x;
    const int base = blockIdx.x * 64;

    for (int i = tid; i < 64 * NNB; i += 256) {
        a2a_l[i] = a2a[base * NNB + i];
        a2b_l[i] = a2b[base * NNB + i];
    }
    __syncthreads();

    // msg gather -> A cols 0..255 (4 cols per task, bf16x4 loads, fp32 sum)
    for (int it = tid; it < 64 * 64; it += 256) {
        int r = it >> 6, ch = it & 63;
        const int* nb = &a2a_l[r * NNB];
        float s0 = 0.f, s1 = 0.f, s2 = 0.f, s3 = 0.f;
#pragma unroll
        for (int t = 0; t < NNB; ++t) {
            ushort4 u = *(const ushort4*)&msg_in[(size_t)nb[t] * HID + ch * 4];
            s0 += bf2f(u.x); s1 += bf2f(u.y); s2 += bf2f(u.z); s3 += bf2f(u.w);
        }
        ushort4 o = { f2bf(s0), f2bf(s1), f2bf(s2), f2bf(s3) };
        *(ushort4*)&As[r * LSH + ch * 4] = o;
    }
    // bond gather -> A cols 256..269 (+pad to 287)
    for (int it = tid; it < 64 * 32; it += 256) {
        int r = it >> 5, c = it & 31;
        float s = 0.f;
        if (c < 14) {
            const int* nb = &a2b_l[r * NNB];
#pragma unroll
            for (int t = 0; t < NNB; ++t)
                s += f_bonds[(size_t)nb[t] * BT + (BT - 14) + c];
        }
        As[r * LSH + HID + c] = f2bf(s);
    }
    __syncthreads();

    const int lane = tid & 63, wave = tid >> 6;
    f32x4 acc[4][4] = {};
    mfma_core<KH, LSH>(As, Wh_t, acc, wave, lane);

    const int lm = lane & 15, quad = lane >> 4;
#pragma unroll
    for (int ct = 0; ct < 4; ++ct) {
        int col = wave * 64 + ct * 16 + lm;
        float bv = bh[col];
#pragma unroll
        for (int rt = 0; rt < 4; ++rt)
#pragma unroll
            for (int i = 0; i < 4; ++i) {
                int row = base + rt * 16 + quad * 4 + i;
                float v = acc[rt][ct][i] + bv + inp[(size_t)row * HID + col];
                msg_out[(size_t)row * HID + col] = f2bf(fmaxf(v, 0.f));
            }
    }
}

// ---------------------------------------------------------------------------
// Kernel 3: hid = relu([gather_a(msg) | atom] @ Wo' + bo)  (fp32 out)
// ---------------------------------------------------------------------------
__global__ __launch_bounds__(256) void k_final(const unsigned short* __restrict__ msg_in,
                                               const float* __restrict__ atom,
                                               const int* __restrict__ a2a,
                                               const unsigned short* __restrict__ Wo_t,
                                               const float* __restrict__ bo,
                                               float* __restrict__ hid) {
    __shared__ unsigned short As[64 * LSO];
    __shared__ int a2a_l[64 * NNB];
    const int tid  = threadIdx.x;
    const int base = blockIdx.x * 64;

    for (int i = tid; i < 64 * NNB; i += 256)
        a2a_l[i] = a2a[base * NNB + i];
    __syncthreads();

    for (int it = tid; it < 64 * 64; it += 256) {
        int r = it >> 6, ch = it & 63;
        const int* nb = &a2a_l[r * NNB];
        float s0 = 0.f, s1 = 0.f, s2 = 0.f, s3 = 0.f;
#pragma unroll
        for (int t = 0; t < NNB; ++t) {
            ushort4 u = *(const ushort4*)&msg_in[(size_t)nb[t] * HID + ch * 4];
            s0 += bf2f(u.x); s1 += bf2f(u.y); s2 += bf2f(u.z); s3 += bf2f(u.w);
        }
        ushort4 o = { f2bf(s0), f2bf(s1), f2bf(s2), f2bf(s3) };
        *(ushort4*)&As[r * LSO + ch * 4] = o;
    }
    // atom features -> A cols 256..388 (+pad to 415)
    for (int it = tid; it < 64 * 160; it += 256) {
        int r = it / 160, c = it - r * 160;
        float v = (c < AF) ? atom[(size_t)(base + r) * AF + c] : 0.f;
        As[r * LSO + HID + c] = f2bf(v);
    }
    __syncthreads();

    const int lane = tid & 63, wave = tid >> 6;
    f32x4 acc[4][4] = {};
    mfma_core<KO, LSO>(As, Wo_t, acc, wave, lane);

    const int lm = lane & 15, quad = lane >> 4;
#pragma unroll
    for (int ct = 0; ct < 4; ++ct) {
        int col = wave * 64 + ct * 16 + lm;
        float bv = bo[col];
#pragma unroll
        for (int rt = 0; rt < 4; ++rt)
#pragma unroll
            for (int i = 0; i < 4; ++i) {
                int row = base + rt * 16 + quad * 4 + i;
                hid[(size_t)row * HID + col] = fmaxf(acc[rt][ct][i] + bv, 0.f);
            }
    }
}

// ---------------------------------------------------------------------------
// Kernel 4: segment mean (sorted segment_ids), one block per molecule.
// ---------------------------------------------------------------------------
__global__ __launch_bounds__(256) void k_segmean(const float* __restrict__ hid,
                                                 const int* __restrict__ seg,
                                                 float* __restrict__ out) {
    const int m = blockIdx.x;
    __shared__ int lohi[2];
    if (threadIdx.x == 0) {
        int lo = 0, hi = N_ATOMS;
        while (lo < hi) { int mid = (lo + hi) >> 1; if (seg[mid] < m) lo = mid + 1; else hi = mid; }
        lohi[0] = lo;
        int lo2 = lo, hi2 = N_ATOMS;
        while (lo2 < hi2) { int mid = (lo2 + hi2) >> 1; if (seg[mid] < m + 1) lo2 = mid + 1; else hi2 = mid; }
        lohi[1] = lo2;
    }
    __syncthreads();
    const int lo = lohi[0], hi = lohi[1];
    const int j = threadIdx.x;
    float s = 0.f;
    for (int i = lo; i < hi; ++i) s += hid[(size_t)i * HID + j];
    const int cnt = hi - lo;
    out[m * HID + j] = (cnt > 0) ? (s / (float)cnt) : 0.f;
}

// ---------------------------------------------------------------------------
extern "C" void kernel_launch(void* const* d_in, const int* in_sizes, int n_in,
                              void* d_out, int out_size, void* d_ws, size_t ws_size,
                              hipStream_t stream) {
    const float* atom    = (const float*)d_in[0];
    const float* f_bonds = (const float*)d_in[1];
    const int*   a2a     = (const int*)d_in[2];
    const int*   a2b     = (const int*)d_in[3];
    const int*   seg     = (const int*)d_in[4];
    const float* Wi      = (const float*)d_in[5];
    const float* bi      = (const float*)d_in[6];
    const float* Wh      = (const float*)d_in[7];
    const float* bh      = (const float*)d_in[8];
    const float* Wo      = (const float*)d_in[9];
    const float* bo      = (const float*)d_in[10];
    float* out = (float*)d_out;

    char* ws = (char*)d_ws;
    const size_t nh = (size_t)N_ATOMS * HID;
    float*          inp  = (float*)ws;                        // 64 MB fp32 (reused as hid)
    unsigned short* msg0 = (unsigned short*)(ws + nh * 4);    // 32 MB bf16
    unsigned short* msg1 = msg0 + nh;                         // 32 MB bf16
    unsigned short* Wi_t = msg1 + nh;
    unsigned short* Wh_t = Wi_t + 256 * KI;
    unsigned short* Wo_t = Wh_t + 256 * KH;
    float*          hid  = inp;                               // inp dead after 2nd k_iter

    dim3 blk(256);
    const int nblk = N_ATOMS / 64;   // 1024

    k_prep<<<256, blk, 0, stream>>>(Wi, Wh, Wo, Wi_t, Wh_t, Wo_t);
    k_inp<<<nblk, blk, 0, stream>>>(atom, Wi_t, bi, inp, msg0);
    k_iter<<<nblk, blk, 0, stream>>>(msg0, inp, f_bonds, a2a, a2b, Wh_t, bh, msg1);
    k_iter<<<nblk, blk, 0, stream>>>(msg1, inp, f_bonds, a2a, a2b, Wh_t, bh, msg0);
    k_final<<<nblk, blk, 0, stream>>>(msg0, atom, a2a, Wo_t, bo, hid);
    k_segmean<<<NM, blk, 0, stream>>>(hid, seg, out);
}

// Round 3
// 434.724 us; speedup vs baseline: 2.0359x; 1.0852x over previous
//
#include <hip/hip_runtime.h>

#define N_ATOMS 65536
#define AF      133     // atom feature dim
#define BT      147     // bond feature total dim
#define HID     256
#define NNB     6
#define NM      2048

// padded K per GEMM (multiples of 32; zero-padded in A and W -> exact)
#define KI   160        // k_inp phase 1: atom(133) + pad
#define KB   32         // k_inp phase 2: bond(14) + pad
#define KH   256        // k_iter: msg only (bond part folded into inp2)
#define KO   416        // k_final: msg(256) + atom(133) + pad
// LDS strides (elements)
#define LSI  168
#define LSH  264
#define LSO  424

typedef __attribute__((ext_vector_type(8))) short short8;
typedef __attribute__((ext_vector_type(4))) float f32x4;

__device__ __forceinline__ unsigned short f2bf(float f) {
    unsigned u = __builtin_bit_cast(unsigned, f);
    u += 0x7fffu + ((u >> 16) & 1u);     // round-to-nearest-even
    return (unsigned short)(u >> 16);
}
__device__ __forceinline__ float bf2f(unsigned short s) {
    unsigned u = ((unsigned)s) << 16;
    return __builtin_bit_cast(float, u);
}

// ---------------------------------------------------------------------------
// Weight prep (bf16, [N=256][K] transposed, K zero-padded):
//   Wi_t [n][k] = Wi[k][n]            (k<133)
//   Wb_t [n][k] = Wh[256+k][n]        (k<14)   bond slice of Wh
//   Whm_t[n][k] = Wh[k][n]            (k<256)  message slice of Wh
//   Wo_t [n][k] = k<256 ? Wo[133+k][n] : Wo[k-256][n] (k<389)
// ---------------------------------------------------------------------------
__global__ __launch_bounds__(256) void k_prep(const float* __restrict__ Wi,
                                              const float* __restrict__ Wh,
                                              const float* __restrict__ Wo,
                                              unsigned short* __restrict__ Wi_t,
                                              unsigned short* __restrict__ Wb_t,
                                              unsigned short* __restrict__ Whm_t,
                                              unsigned short* __restrict__ Wo_t) {
    const int n = blockIdx.x;
    for (int k = threadIdx.x; k < KI; k += 256)
        Wi_t[n * KI + k] = f2bf(k < AF ? Wi[k * HID + n] : 0.f);
    for (int k = threadIdx.x; k < KB; k += 256)
        Wb_t[n * KB + k] = f2bf(k < 14 ? Wh[(HID + k) * HID + n] : 0.f);
    for (int k = threadIdx.x; k < KH; k += 256)
        Whm_t[n * KH + k] = f2bf(Wh[k * HID + n]);
    for (int k = threadIdx.x; k < KO; k += 256) {
        float v = 0.f;
        if (k < HID)            v = Wo[(AF + k) * HID + n];
        else if (k < HID + AF)  v = Wo[(k - HID) * HID + n];
        Wo_t[n * KO + k] = f2bf(v);
    }
}

// ---------------------------------------------------------------------------
// MFMA core: C[RT*16 x 256] += A_lds[RT*16 x K](bf16) @ W_t[256 x K]^T
// wave w owns cols w*64..w*64+63 (4 col-tiles of 16).
// ---------------------------------------------------------------------------
template<int K, int LS, int RT>
__device__ __forceinline__ void mfma_core(const unsigned short* __restrict__ As,
                                          const unsigned short* __restrict__ Wt,
                                          f32x4 (&acc)[RT][4], int wave, int lane) {
    const int lm = lane & 15, quad = lane >> 4;
    for (int ks = 0; ks < K; ks += 32) {
        short8 af[RT], bf[4];
#pragma unroll
        for (int rt = 0; rt < RT; ++rt)
            af[rt] = *(const short8*)&As[(rt * 16 + lm) * LS + ks + quad * 8];
#pragma unroll
        for (int ct = 0; ct < 4; ++ct)
            bf[ct] = *(const short8*)&Wt[(size_t)(wave * 64 + ct * 16 + lm) * K + ks + quad * 8];
#pragma unroll
        for (int rt = 0; rt < RT; ++rt)
#pragma unroll
            for (int ct = 0; ct < 4; ++ct)
                acc[rt][ct] = __builtin_amdgcn_mfma_f32_16x16x32_bf16(af[rt], bf[ct], acc[rt][ct], 0, 0, 0);
    }
}

// ---------------------------------------------------------------------------
// Kernel 1 (64-row tiles): two-phase.
//   phase1: acc = atom @ Wi          -> msg0 = relu(acc + bi)       (bf16)
//   phase2: acc += bond_sum @ Wb     -> inp2 = acc + bi + bh        (bf16)
// (inp2 = inp + bh + bond-part of m; loop-invariant across iterations)
// ---------------------------------------------------------------------------
__global__ __launch_bounds__(256) void k_inp(const float* __restrict__ atom,
                                             const float* __restrict__ f_bonds,
                                             const int* __restrict__ a2b,
                                             const unsigned short* __restrict__ Wi_t,
                                             const unsigned short* __restrict__ Wb_t,
                                             const float* __restrict__ bi,
                                             const float* __restrict__ bh,
                                             unsigned short* __restrict__ msg,
                                             unsigned short* __restrict__ inp2) {
    __shared__ unsigned short As[64 * LSI];
    __shared__ unsigned short Bs[64 * KB];
    __shared__ int a2b_l[64 * NNB];
    const int tid  = threadIdx.x;
    const int base = blockIdx.x * 64;

    for (int i = tid; i < 64 * NNB; i += 256)
        a2b_l[i] = a2b[base * NNB + i];

    for (int it = tid; it < 64 * KI; it += 256) {
        int r = it / KI, c = it - r * KI;
        float v = (c < AF) ? atom[(size_t)(base + r) * AF + c] : 0.f;
        As[r * LSI + c] = f2bf(v);
    }
    __syncthreads();   // a2b_l ready

    for (int it = tid; it < 64 * KB; it += 256) {
        int r = it >> 5, c = it & 31;
        float s = 0.f;
        if (c < 14) {
            const int* nb = &a2b_l[r * NNB];
#pragma unroll
            for (int t = 0; t < NNB; ++t)
                s += f_bonds[(size_t)nb[t] * BT + (BT - 14) + c];
        }
        Bs[r * KB + c] = f2bf(s);
    }
    __syncthreads();

    const int lane = tid & 63, wave = tid >> 6;
    const int lm = lane & 15, quad = lane >> 4;
    f32x4 acc[4][4] = {};

    mfma_core<KI, LSI, 4>(As, Wi_t, acc, wave, lane);

    // msg = relu(inp), inp = acc + bi
#pragma unroll
    for (int ct = 0; ct < 4; ++ct) {
        int col = wave * 64 + ct * 16 + lm;
        float bv = bi[col];
#pragma unroll
        for (int rt = 0; rt < 4; ++rt)
#pragma unroll
            for (int i = 0; i < 4; ++i) {
                int row = base + rt * 16 + quad * 4 + i;
                msg[(size_t)row * HID + col] = f2bf(fmaxf(acc[rt][ct][i] + bv, 0.f));
            }
    }

    mfma_core<KB, KB, 4>(Bs, Wb_t, acc, wave, lane);

    // inp2 = inp + bh + bond_part = acc + bi + bh
#pragma unroll
    for (int ct = 0; ct < 4; ++ct) {
        int col = wave * 64 + ct * 16 + lm;
        float bv = bi[col] + bh[col];
#pragma unroll
        for (int rt = 0; rt < 4; ++rt)
#pragma unroll
            for (int i = 0; i < 4; ++i) {
                int row = base + rt * 16 + quad * 4 + i;
                inp2[(size_t)row * HID + col] = f2bf(acc[rt][ct][i] + bv);
            }
    }
}

// ---------------------------------------------------------------------------
// Kernel 2 (32-row tiles): msg_out = relu(inp2 + gather_a(msg) @ Whm)
// ---------------------------------------------------------------------------
__global__ __launch_bounds__(256, 4) void k_iter(const unsigned short* __restrict__ msg_in,
                                                 const unsigned short* __restrict__ inp2,
                                                 const int* __restrict__ a2a,
                                                 const unsigned short* __restrict__ Whm_t,
                                                 unsigned short* __restrict__ msg_out) {
    __shared__ unsigned short As[32 * LSH];
    __shared__ int a2a_l[32 * NNB];
    const int tid  = threadIdx.x;
    const int base = blockIdx.x * 32;

    for (int i = tid; i < 32 * NNB; i += 256)
        a2a_l[i] = a2a[base * NNB + i];
    __syncthreads();

    // gather-sum 6 random msg rows per output row; 16B loads, fp32 sums
    for (int it = tid; it < 32 * 32; it += 256) {
        int r = it >> 5, ch = it & 31;
        const int* nb = &a2a_l[r * NNB];
        float s[8] = {};
#pragma unroll
        for (int t = 0; t < NNB; ++t) {
            short8 u = *(const short8*)&msg_in[(size_t)nb[t] * HID + ch * 8];
#pragma unroll
            for (int j = 0; j < 8; ++j) s[j] += bf2f((unsigned short)u[j]);
        }
        short8 o;
#pragma unroll
        for (int j = 0; j < 8; ++j) o[j] = (short)f2bf(s[j]);
        *(short8*)&As[r * LSH + ch * 8] = o;
    }
    __syncthreads();

    const int lane = tid & 63, wave = tid >> 6;
    f32x4 acc[2][4] = {};
    mfma_core<KH, LSH, 2>(As, Whm_t, acc, wave, lane);

    const int lm = lane & 15, quad = lane >> 4;
#pragma unroll
    for (int ct = 0; ct < 4; ++ct) {
        int col = wave * 64 + ct * 16 + lm;
#pragma unroll
        for (int rt = 0; rt < 2; ++rt)
#pragma unroll
            for (int i = 0; i < 4; ++i) {
                int row = base + rt * 16 + quad * 4 + i;
                float v = acc[rt][ct][i] + bf2f(inp2[(size_t)row * HID + col]);
                msg_out[(size_t)row * HID + col] = f2bf(fmaxf(v, 0.f));
            }
    }
}

// ---------------------------------------------------------------------------
// Kernel 3 (32-row tiles): hid = relu([gather_a(msg) | atom] @ Wo' + bo) (bf16)
// ---------------------------------------------------------------------------
__global__ __launch_bounds__(256, 4) void k_final(const unsigned short* __restrict__ msg_in,
                                                  const float* __restrict__ atom,
                                                  const int* __restrict__ a2a,
                                                  const unsigned short* __restrict__ Wo_t,
                                                  const float* __restrict__ bo,
                                                  unsigned short* __restrict__ hid) {
    __shared__ unsigned short As[32 * LSO];
    __shared__ int a2a_l[32 * NNB];
    const int tid  = threadIdx.x;
    const int base = blockIdx.x * 32;

    for (int i = tid; i < 32 * NNB; i += 256)
        a2a_l[i] = a2a[base * NNB + i];
    __syncthreads();

    for (int it = tid; it < 32 * 32; it += 256) {
        int r = it >> 5, ch = it & 31;
        const int* nb = &a2a_l[r * NNB];
        float s[8] = {};
#pragma unroll
        for (int t = 0; t < NNB; ++t) {
            short8 u = *(const short8*)&msg_in[(size_t)nb[t] * HID + ch * 8];
#pragma unroll
            for (int j = 0; j < 8; ++j) s[j] += bf2f((unsigned short)u[j]);
        }
        short8 o;
#pragma unroll
        for (int j = 0; j < 8; ++j) o[j] = (short)f2bf(s[j]);
        *(short8*)&As[r * LSO + ch * 8] = o;
    }
    // atom features -> A cols 256..388 (+pad to 415)
    for (int it = tid; it < 32 * 160; it += 256) {
        int r = it / 160, c = it - r * 160;
        float v = (c < AF) ? atom[(size_t)(base + r) * AF + c] : 0.f;
        As[r * LSO + HID + c] = f2bf(v);
    }
    __syncthreads();

    const int lane = tid & 63, wave = tid >> 6;
    f32x4 acc[2][4] = {};
    mfma_core<KO, LSO, 2>(As, Wo_t, acc, wave, lane);

    const int lm = lane & 15, quad = lane >> 4;
#pragma unroll
    for (int ct = 0; ct < 4; ++ct) {
        int col = wave * 64 + ct * 16 + lm;
        float bv = bo[col];
#pragma unroll
        for (int rt = 0; rt < 2; ++rt)
#pragma unroll
            for (int i = 0; i < 4; ++i) {
                int row = base + rt * 16 + quad * 4 + i;
                hid[(size_t)row * HID + col] = f2bf(fmaxf(acc[rt][ct][i] + bv, 0.f));
            }
    }
}

// ---------------------------------------------------------------------------
// Kernel 4: segment mean (sorted segment_ids), one block per molecule.
// ---------------------------------------------------------------------------
__global__ __launch_bounds__(256) void k_segmean(const unsigned short* __restrict__ hid,
                                                 const int* __restrict__ seg,
                                                 float* __restrict__ out) {
    const int m = blockIdx.x;
    __shared__ int lohi[2];
    if (threadIdx.x == 0) {
        int lo = 0, hi = N_ATOMS;
        while (lo < hi) { int mid = (lo + hi) >> 1; if (seg[mid] < m) lo = mid + 1; else hi = mid; }
        lohi[0] = lo;
        int lo2 = lo, hi2 = N_ATOMS;
        while (lo2 < hi2) { int mid = (lo2 + hi2) >> 1; if (seg[mid] < m + 1) lo2 = mid + 1; else hi2 = mid; }
        lohi[1] = lo2;
    }
    __syncthreads();
    const int lo = lohi[0], hi = lohi[1];
    const int j = threadIdx.x;
    float s = 0.f;
    for (int i = lo; i < hi; ++i) s += bf2f(hid[(size_t)i * HID + j]);
    const int cnt = hi - lo;
    out[m * HID + j] = (cnt > 0) ? (s / (float)cnt) : 0.f;
}

// ---------------------------------------------------------------------------
extern "C" void kernel_launch(void* const* d_in, const int* in_sizes, int n_in,
                              void* d_out, int out_size, void* d_ws, size_t ws_size,
                              hipStream_t stream) {
    const float* atom    = (const float*)d_in[0];
    const float* f_bonds = (const float*)d_in[1];
    const int*   a2a     = (const int*)d_in[2];
    const int*   a2b     = (const int*)d_in[3];
    const int*   seg     = (const int*)d_in[4];
    const float* Wi      = (const float*)d_in[5];
    const float* bi      = (const float*)d_in[6];
    const float* Wh      = (const float*)d_in[7];
    const float* bh      = (const float*)d_in[8];
    const float* Wo      = (const float*)d_in[9];
    const float* bo      = (const float*)d_in[10];
    float* out = (float*)d_out;

    unsigned short* ws = (unsigned short*)d_ws;
    const size_t nh = (size_t)N_ATOMS * HID;
    unsigned short* msg0 = ws;              // 32 MB bf16
    unsigned short* msg1 = msg0 + nh;       // 32 MB bf16
    unsigned short* inp2 = msg1 + nh;       // 32 MB bf16
    unsigned short* Wi_t  = inp2 + nh;
    unsigned short* Wb_t  = Wi_t + 256 * KI;
    unsigned short* Whm_t = Wb_t + 256 * KB;
    unsigned short* Wo_t  = Whm_t + 256 * KH;
    unsigned short* hid   = msg1;           // msg1 dead after 2nd k_iter

    dim3 blk(256);

    k_prep<<<256, blk, 0, stream>>>(Wi, Wh, Wo, Wi_t, Wb_t, Whm_t, Wo_t);
    k_inp<<<N_ATOMS / 64, blk, 0, stream>>>(atom, f_bonds, a2b, Wi_t, Wb_t, bi, bh, msg0, inp2);
    k_iter<<<N_ATOMS / 32, blk, 0, stream>>>(msg0, inp2, a2a, Whm_t, msg1);
    k_iter<<<N_ATOMS / 32, blk, 0, stream>>>(msg1, inp2, a2a, Whm_t, msg0);
    k_final<<<N_ATOMS / 32, blk, 0, stream>>>(msg0, atom, a2a, Wo_t, bo, hid);
    k_segmean<<<NM, blk, 0, stream>>>(hid, seg, out);
}

// Round 4
// 423.968 us; speedup vs baseline: 2.0876x; 1.0254x over previous
//
#include <hip/hip_runtime.h>

#define N_ATOMS 65536
#define AF      133     // atom feature dim
#define BT      147     // bond feature total dim
#define HID     256
#define NNB     6
#define NM      2048

#define KI   160        // atom(133) padded
#define KB   32         // bond(14) padded
#define KP   256        // proj GEMMs (exact)
// LDS strides (elements)
#define LSI  168
#define LSB  40
#define LSP  264

typedef __attribute__((ext_vector_type(8))) short short8;
typedef __attribute__((ext_vector_type(4))) float f32x4;

__device__ __forceinline__ unsigned short f2bf(float f) {
    unsigned u = __builtin_bit_cast(unsigned, f);
    u += 0x7fffu + ((u >> 16) & 1u);     // round-to-nearest-even
    return (unsigned short)(u >> 16);
}
__device__ __forceinline__ float bf2f(unsigned short s) {
    unsigned u = ((unsigned)s) << 16;
    return __builtin_bit_cast(float, u);
}

// ---------------------------------------------------------------------------
// k_prep_bond (grid-partitioned):
//  blocks 0..255: weight transposes to bf16 [N=256][K]:
//    Wi_t [n][k]=Wi[k][n] (k<133)      Wb_t [n][k]=Wh[256+k][n] (k<14)
//    Whm_t[n][k]=Wh[k][n] (k<256)      Woa_t[n][k]=Wo[k][n] (k<133)
//    Wom_t[n][k]=Wo[133+k][n] (k<256)
//  blocks 256+: bondsum[atom][32] = sum_t f_bonds[a2b[atom,t], -14:] (bf16,
//    cols 14..31 zero) — one thread per (atom, c) pair, 1M threads.
// ---------------------------------------------------------------------------
__global__ __launch_bounds__(256) void k_prep_bond(const float* __restrict__ Wi,
                                                   const float* __restrict__ Wh,
                                                   const float* __restrict__ Wo,
                                                   const float* __restrict__ f_bonds,
                                                   const int* __restrict__ a2b,
                                                   unsigned short* __restrict__ Wi_t,
                                                   unsigned short* __restrict__ Wb_t,
                                                   unsigned short* __restrict__ Whm_t,
                                                   unsigned short* __restrict__ Woa_t,
                                                   unsigned short* __restrict__ Wom_t,
                                                   unsigned short* __restrict__ bondsum) {
    if (blockIdx.x < 256) {
        const int n = blockIdx.x;
        for (int k = threadIdx.x; k < KI; k += 256) {
            Wi_t[n * KI + k]  = f2bf(k < AF ? Wi[k * HID + n] : 0.f);
            Woa_t[n * KI + k] = f2bf(k < AF ? Wo[k * HID + n] : 0.f);
        }
        for (int k = threadIdx.x; k < KB; k += 256)
            Wb_t[n * KB + k] = f2bf(k < 14 ? Wh[(HID + k) * HID + n] : 0.f);
        for (int k = threadIdx.x; k < KP; k += 256) {
            Whm_t[n * KP + k] = f2bf(Wh[k * HID + n]);
            Wom_t[n * KP + k] = f2bf(Wo[(AF + k) * HID + n]);
        }
    } else {
        const int id   = (blockIdx.x - 256) * 256 + threadIdx.x;  // 1M threads
        const int atom = id >> 4;
        const int c    = id & 15;
        float s = 0.f;
        if (c < 14) {
            const int* nb = &a2b[atom * NNB];
#pragma unroll
            for (int t = 0; t < NNB; ++t)
                s += f_bonds[(size_t)nb[t] * BT + (BT - 14) + c];
        }
        bondsum[atom * 32 + c]      = f2bf(s);
        bondsum[atom * 32 + 16 + c] = 0;
    }
}

// ---------------------------------------------------------------------------
// MFMA core: C[RT*16 x 256] += A_lds[RT*16 x K](bf16) @ W_t[256 x K]^T
// ---------------------------------------------------------------------------
template<int K, int LS, int RT>
__device__ __forceinline__ void mfma_core(const unsigned short* __restrict__ As,
                                          const unsigned short* __restrict__ Wt,
                                          f32x4 (&acc)[RT][4], int wave, int lane) {
    const int lm = lane & 15, quad = lane >> 4;
    for (int ks = 0; ks < K; ks += 32) {
        short8 af[RT], bf[4];
#pragma unroll
        for (int rt = 0; rt < RT; ++rt)
            af[rt] = *(const short8*)&As[(rt * 16 + lm) * LS + ks + quad * 8];
#pragma unroll
        for (int ct = 0; ct < 4; ++ct)
            bf[ct] = *(const short8*)&Wt[(size_t)(wave * 64 + ct * 16 + lm) * K + ks + quad * 8];
#pragma unroll
        for (int rt = 0; rt < RT; ++rt)
#pragma unroll
            for (int ct = 0; ct < 4; ++ct)
                acc[rt][ct] = __builtin_amdgcn_mfma_f32_16x16x32_bf16(af[rt], bf[ct], acc[rt][ct], 0, 0, 0);
    }
}

// ---------------------------------------------------------------------------
// k_inp (64-row tiles), all dense:
//   acc  = atom @ Wi              -> msg0 = relu(acc + bi)
//   acc += bondsum @ Wb           -> inp2 = acc + bi + bh
//   acc2 = atom @ Wo_a            -> aw   = acc2 + bo
// ---------------------------------------------------------------------------
__global__ __launch_bounds__(256) void k_inp(const float* __restrict__ atom,
                                             const unsigned short* __restrict__ bondsum,
                                             const unsigned short* __restrict__ Wi_t,
                                             const unsigned short* __restrict__ Wb_t,
                                             const unsigned short* __restrict__ Woa_t,
                                             const float* __restrict__ bi,
                                             const float* __restrict__ bh,
                                             const float* __restrict__ bo,
                                             unsigned short* __restrict__ msg,
                                             unsigned short* __restrict__ inp2,
                                             unsigned short* __restrict__ aw) {
    __shared__ unsigned short As[64 * LSI];
    __shared__ unsigned short Bs[64 * LSB];
    const int tid  = threadIdx.x;
    const int base = blockIdx.x * 64;

    for (int it = tid; it < 64 * KI; it += 256) {
        int r = it / KI, c = it - r * KI;
        float v = (c < AF) ? atom[(size_t)(base + r) * AF + c] : 0.f;
        As[r * LSI + c] = f2bf(v);
    }
    {   // bondsum rows are [32]-wide bf16, coalesced copy with pad stride
        int r = tid >> 2, c = (tid & 3) * 8;    // 256 threads cover 64x32
        *(short8*)&Bs[r * LSB + c] = *(const short8*)&bondsum[(size_t)(base + r) * 32 + c];
    }
    __syncthreads();

    const int lane = tid & 63, wave = tid >> 6;
    const int lm = lane & 15, quad = lane >> 4;
    f32x4 acc[4][4] = {};

    mfma_core<KI, LSI, 4>(As, Wi_t, acc, wave, lane);

#pragma unroll
    for (int ct = 0; ct < 4; ++ct) {
        int col = wave * 64 + ct * 16 + lm;
        float bv = bi[col];
#pragma unroll
        for (int rt = 0; rt < 4; ++rt)
#pragma unroll
            for (int i = 0; i < 4; ++i) {
                int row = base + rt * 16 + quad * 4 + i;
                msg[(size_t)row * HID + col] = f2bf(fmaxf(acc[rt][ct][i] + bv, 0.f));
            }
    }

    mfma_core<KB, LSB, 4>(Bs, Wb_t, acc, wave, lane);

#pragma unroll
    for (int ct = 0; ct < 4; ++ct) {
        int col = wave * 64 + ct * 16 + lm;
        float bv = bi[col] + bh[col];
#pragma unroll
        for (int rt = 0; rt < 4; ++rt)
#pragma unroll
            for (int i = 0; i < 4; ++i) {
                int row = base + rt * 16 + quad * 4 + i;
                inp2[(size_t)row * HID + col] = f2bf(acc[rt][ct][i] + bv);
            }
    }

    f32x4 acc2[4][4] = {};
    mfma_core<KI, LSI, 4>(As, Woa_t, acc2, wave, lane);

#pragma unroll
    for (int ct = 0; ct < 4; ++ct) {
        int col = wave * 64 + ct * 16 + lm;
        float bv = bo[col];
#pragma unroll
        for (int rt = 0; rt < 4; ++rt)
#pragma unroll
            for (int i = 0; i < 4; ++i) {
                int row = base + rt * 16 + quad * 4 + i;
                aw[(size_t)row * HID + col] = f2bf(acc2[rt][ct][i] + bv);
            }
    }
}

// ---------------------------------------------------------------------------
// k_proj (64-row tiles): P = X @ W_t^T, dense streaming GEMM, bf16 out.
// ---------------------------------------------------------------------------
__global__ __launch_bounds__(256, 4) void k_proj(const unsigned short* __restrict__ X,
                                                 const unsigned short* __restrict__ Wt,
                                                 unsigned short* __restrict__ P) {
    __shared__ unsigned short As[64 * LSP];
    const int tid  = threadIdx.x;
    const int base = blockIdx.x * 64;

    for (int it = tid; it < 64 * 32; it += 256) {
        int r = it >> 5, ch = it & 31;
        *(short8*)&As[r * LSP + ch * 8] = *(const short8*)&X[(size_t)(base + r) * HID + ch * 8];
    }
    __syncthreads();

    const int lane = tid & 63, wave = tid >> 6;
    f32x4 acc[4][4] = {};
    mfma_core<KP, LSP, 4>(As, Wt, acc, wave, lane);

    const int lm = lane & 15, quad = lane >> 4;
#pragma unroll
    for (int ct = 0; ct < 4; ++ct) {
        int col = wave * 64 + ct * 16 + lm;
#pragma unroll
        for (int rt = 0; rt < 4; ++rt)
#pragma unroll
            for (int i = 0; i < 4; ++i) {
                int row = base + rt * 16 + quad * 4 + i;
                P[(size_t)row * HID + col] = f2bf(acc[rt][ct][i]);
            }
    }
}

// ---------------------------------------------------------------------------
// k_gath: out[i] = relu(base_[i] + sum_t P[a2a[i,t]])   (all bf16 rows)
// one thread per (atom, 8-channel group): 2M threads, 6 independent 16B loads.
// ---------------------------------------------------------------------------
__global__ __launch_bounds__(256) void k_gath(const unsigned short* __restrict__ P,
                                              const unsigned short* __restrict__ base_,
                                              const int* __restrict__ a2a,
                                              unsigned short* __restrict__ out) {
    __shared__ int nb_l[8 * NNB];
    const int tid  = threadIdx.x;
    const int ablk = blockIdx.x * 8;
    if (tid < 8 * NNB) nb_l[tid] = a2a[ablk * NNB + tid];
    __syncthreads();

    const int a  = tid >> 5;      // local atom 0..7
    const int cg = tid & 31;      // 8-channel group
    const int* nb = &nb_l[a * NNB];

    float s[8] = {};
#pragma unroll
    for (int t = 0; t < NNB; ++t) {
        short8 u = *(const short8*)&P[(size_t)nb[t] * HID + cg * 8];
#pragma unroll
        for (int j = 0; j < 8; ++j) s[j] += bf2f((unsigned short)u[j]);
    }
    const size_t row = (size_t)(ablk + a);
    short8 b = *(const short8*)&base_[row * HID + cg * 8];
    short8 o;
#pragma unroll
    for (int j = 0; j < 8; ++j)
        o[j] = (short)f2bf(fmaxf(s[j] + bf2f((unsigned short)b[j]), 0.f));
    *(short8*)&out[row * HID + cg * 8] = o;
}

// ---------------------------------------------------------------------------
// k_segmean: segment mean over sorted segment_ids, one block per molecule.
// ---------------------------------------------------------------------------
__global__ __launch_bounds__(256) void k_segmean(const unsigned short* __restrict__ hid,
                                                 const int* __restrict__ seg,
                                                 float* __restrict__ out) {
    const int m = blockIdx.x;
    __shared__ int lohi[2];
    if (threadIdx.x == 0) {
        int lo = 0, hi = N_ATOMS;
        while (lo < hi) { int mid = (lo + hi) >> 1; if (seg[mid] < m) lo = mid + 1; else hi = mid; }
        lohi[0] = lo;
        int lo2 = lo, hi2 = N_ATOMS;
        while (lo2 < hi2) { int mid = (lo2 + hi2) >> 1; if (seg[mid] < m + 1) lo2 = mid + 1; else hi2 = mid; }
        lohi[1] = lo2;
    }
    __syncthreads();
    const int lo = lohi[0], hi = lohi[1];
    const int j = threadIdx.x;
    float s = 0.f;
    for (int i = lo; i < hi; ++i) s += bf2f(hid[(size_t)i * HID + j]);
    const int cnt = hi - lo;
    out[m * HID + j] = (cnt > 0) ? (s / (float)cnt) : 0.f;
}

// ---------------------------------------------------------------------------
extern "C" void kernel_launch(void* const* d_in, const int* in_sizes, int n_in,
                              void* d_out, int out_size, void* d_ws, size_t ws_size,
                              hipStream_t stream) {
    const float* atom    = (const float*)d_in[0];
    const float* f_bonds = (const float*)d_in[1];
    const int*   a2a     = (const int*)d_in[2];
    const int*   a2b     = (const int*)d_in[3];
    const int*   seg     = (const int*)d_in[4];
    const float* Wi      = (const float*)d_in[5];
    const float* bi      = (const float*)d_in[6];
    const float* Wh      = (const float*)d_in[7];
    const float* bh      = (const float*)d_in[8];
    const float* Wo      = (const float*)d_in[9];
    const float* bo      = (const float*)d_in[10];
    float* out = (float*)d_out;

    unsigned short* ws = (unsigned short*)d_ws;
    const size_t nh = (size_t)N_ATOMS * HID;
    unsigned short* msg0 = ws;               // 32 MB
    unsigned short* msg1 = msg0 + nh;        // 32 MB
    unsigned short* inp2 = msg1 + nh;        // 32 MB
    unsigned short* aw   = inp2 + nh;        // 32 MB
    unsigned short* P    = aw + nh;          // 32 MB
    unsigned short* bsum = P + nh;           // 4 MB (65536 x 32)
    unsigned short* Wi_t  = bsum + (size_t)N_ATOMS * 32;
    unsigned short* Wb_t  = Wi_t + 256 * KI;
    unsigned short* Whm_t = Wb_t + 256 * KB;
    unsigned short* Woa_t = Whm_t + 256 * KP;
    unsigned short* Wom_t = Woa_t + 256 * KI;

    dim3 blk(256);

    k_prep_bond<<<256 + N_ATOMS * 16 / 256, blk, 0, stream>>>(
        Wi, Wh, Wo, f_bonds, a2b, Wi_t, Wb_t, Whm_t, Woa_t, Wom_t, bsum);
    k_inp<<<N_ATOMS / 64, blk, 0, stream>>>(
        atom, bsum, Wi_t, Wb_t, Woa_t, bi, bh, bo, msg0, inp2, aw);

    k_proj<<<N_ATOMS / 64, blk, 0, stream>>>(msg0, Whm_t, P);
    k_gath<<<N_ATOMS / 8, blk, 0, stream>>>(P, inp2, a2a, msg1);

    k_proj<<<N_ATOMS / 64, blk, 0, stream>>>(msg1, Whm_t, P);
    k_gath<<<N_ATOMS / 8, blk, 0, stream>>>(P, inp2, a2a, msg0);

    k_proj<<<N_ATOMS / 64, blk, 0, stream>>>(msg0, Wom_t, P);
    k_gath<<<N_ATOMS / 8, blk, 0, stream>>>(P, aw, a2a, msg1);   // hid = msg1

    k_segmean<<<NM, blk, 0, stream>>>(msg1, seg, out);
}